// Round 1
// baseline (486.008 us; speedup 1.0000x reference)
//
#include <hip/hip_runtime.h>
#include <stdint.h>

typedef unsigned short ushort_t;
typedef __bf16 bf16x8 __attribute__((ext_vector_type(8)));
typedef float f32x4 __attribute__((ext_vector_type(4)));

#define DIM 1024
#define HEADS 16
#define HD 64
#define BATCH 2
#define SEQ 2048
#define MTOT (BATCH*SEQ)   // 4096

__device__ __forceinline__ ushort_t f2bf(float f) {
    uint32_t u = __float_as_uint(f);
    uint32_t r = (u + 0x7FFFu + ((u >> 16) & 1u)) >> 16;
    return (ushort_t)r;
}

__device__ __forceinline__ f32x4 mfma16(bf16x8 a, bf16x8 b, f32x4 c) {
    return __builtin_amdgcn_mfma_f32_16x16x32_bf16(a, b, c, 0, 0, 0);
}

// ---------------- convert x: fp32 -> bf16 ----------------
__global__ void k_conv_x(const float* __restrict__ x, ushort_t* __restrict__ xb, int n4) {
    int i = blockIdx.x * blockDim.x + threadIdx.x;
    if (i < n4) {
        const float4 v = ((const float4*)x)[i];
        ushort4 o;
        o.x = f2bf(v.x); o.y = f2bf(v.y); o.z = f2bf(v.z); o.w = f2bf(v.w);
        ((ushort4*)xb)[i] = o;
    }
}

// ---------------- transpose + convert weights: wT[n][k] = bf16(w[k][n]) ----------------
__global__ void k_transpose_w(const float* __restrict__ w0, const float* __restrict__ w1,
                              const float* __restrict__ w2, const float* __restrict__ w3,
                              ushort_t* __restrict__ wt) {
    __shared__ float t[32][33];
    const float* w = (blockIdx.z == 0) ? w0 : (blockIdx.z == 1) ? w1 : (blockIdx.z == 2) ? w2 : w3;
    ushort_t* o = wt + (size_t)blockIdx.z * DIM * DIM;
    int n0 = blockIdx.x * 32;
    int k0 = blockIdx.y * 32;
    int tx = threadIdx.x, ty = threadIdx.y; // (32, 8)
#pragma unroll
    for (int i = 0; i < 4; i++)
        t[ty + i * 8][tx] = w[(size_t)(k0 + ty + i * 8) * DIM + n0 + tx];
    __syncthreads();
#pragma unroll
    for (int i = 0; i < 4; i++)
        o[(size_t)(n0 + ty + i * 8) * DIM + k0 + tx] = f2bf(t[tx][ty + i * 8]);
}

// ---------------- fused QKV projection GEMM ----------------
// C[m][n] = sum_k xb[m][k] * wT[n][k];  scatter into attention-friendly layouts.
// z=0: Qh[b][h][s][i] ; z=1: Kh[b][h][s][i] ; z=2: Vt[b][h][i][s]   (n = i*16+h)
__global__ __launch_bounds__(256) void k_qkv(const ushort_t* __restrict__ xb,
                                             const ushort_t* __restrict__ wt,
                                             ushort_t* __restrict__ qh,
                                             ushort_t* __restrict__ kh,
                                             ushort_t* __restrict__ vt) {
    const int z = blockIdx.z;
    const ushort_t* w = wt + (size_t)z * DIM * DIM;
    const int tid = threadIdx.x;
    const int wave = tid >> 6;
    const int lane = tid & 63;
    const int l16 = lane & 15;
    const int quad = lane >> 4;
    const int m0 = blockIdx.x * 128 + (wave & 1) * 64;
    const int n0 = blockIdx.y * 128 + (wave >> 1) * 64;

    const f32x4 zero4 = {0.f, 0.f, 0.f, 0.f};
    f32x4 acc[4][4];
#pragma unroll
    for (int i = 0; i < 4; i++)
#pragma unroll
        for (int j = 0; j < 4; j++) acc[i][j] = zero4;

    const ushort_t* aptr = xb + (size_t)(m0 + l16) * DIM + quad * 8;
    const ushort_t* bptr = w  + (size_t)(n0 + l16) * DIM + quad * 8;

    for (int k = 0; k < DIM; k += 32) {
        bf16x8 a[4], b[4];
#pragma unroll
        for (int i = 0; i < 4; i++) {
            a[i] = *(const bf16x8*)(aptr + (size_t)i * 16 * DIM + k);
            b[i] = *(const bf16x8*)(bptr + (size_t)i * 16 * DIM + k);
        }
#pragma unroll
        for (int mi = 0; mi < 4; mi++)
#pragma unroll
            for (int ni = 0; ni < 4; ni++)
                acc[mi][ni] = mfma16(a[mi], b[ni], acc[mi][ni]);
    }

#pragma unroll
    for (int mi = 0; mi < 4; mi++) {
#pragma unroll
        for (int ni = 0; ni < 4; ni++) {
            int col = n0 + ni * 16 + l16;
            int ii = col >> 4;
            int hh = col & 15;
#pragma unroll
            for (int r = 0; r < 4; r++) {
                int row = m0 + mi * 16 + quad * 4 + r;
                int bb = row >> 11;
                int ss = row & 2047;
                ushort_t val = f2bf(acc[mi][ni][r]);
                if (z == 0)
                    qh[(((size_t)bb * HEADS + hh) * SEQ + ss) * HD + ii] = val;
                else if (z == 1)
                    kh[(((size_t)bb * HEADS + hh) * SEQ + ss) * HD + ii] = val;
                else
                    vt[(((size_t)bb * HEADS + hh) * HD + ii) * SEQ + ss] = val;
            }
        }
    }
}

// ---------------- flash attention (per-wave, 16 Q-rows, 32-wide KV tiles) ----------------
__global__ __launch_bounds__(256) void k_attn(const ushort_t* __restrict__ qh,
                                              const ushort_t* __restrict__ kh,
                                              const ushort_t* __restrict__ vt,
                                              ushort_t* __restrict__ merged) {
    __shared__ __align__(16) ushort_t plds[4][16][40]; // per-wave P tile, padded stride
    const int tid = threadIdx.x;
    const int wv = tid >> 6;
    const int lane = tid & 63;
    const int l16 = lane & 15;
    const int quad = lane >> 4;
    const int bh = blockIdx.y;
    const int q0 = blockIdx.x * 64 + wv * 16;

    const ushort_t* Q = qh + (size_t)bh * SEQ * HD;
    const ushort_t* K = kh + (size_t)bh * SEQ * HD;
    const ushort_t* V = vt + (size_t)bh * HD * SEQ;

    bf16x8 qa0 = *(const bf16x8*)(Q + (size_t)(q0 + l16) * HD + quad * 8);
    bf16x8 qa1 = *(const bf16x8*)(Q + (size_t)(q0 + l16) * HD + 32 + quad * 8);

    const f32x4 zero4 = {0.f, 0.f, 0.f, 0.f};
    f32x4 oacc[4];
#pragma unroll
    for (int i = 0; i < 4; i++) oacc[i] = zero4;
    float mI[4], lI[4];
#pragma unroll
    for (int r = 0; r < 4; r++) { mI[r] = -3.0e38f; lI[r] = 0.f; }

    const int nt = (q0 + 47) >> 5;
    for (int kt = 0; kt < nt; kt++) {
        int kb = kt * 32;
        bf16x8 k0a = *(const bf16x8*)(K + (size_t)(kb + l16) * HD + quad * 8);
        bf16x8 k0b = *(const bf16x8*)(K + (size_t)(kb + l16) * HD + 32 + quad * 8);
        bf16x8 k1a = *(const bf16x8*)(K + (size_t)(kb + 16 + l16) * HD + quad * 8);
        bf16x8 k1b = *(const bf16x8*)(K + (size_t)(kb + 16 + l16) * HD + 32 + quad * 8);

        f32x4 s0 = zero4, s1 = zero4;
        s0 = mfma16(qa0, k0a, s0);
        s0 = mfma16(qa1, k0b, s0);
        s1 = mfma16(qa0, k1a, s1);
        s1 = mfma16(qa1, k1b, s1);

        const float scale = 0.03125f; // 1/sqrt(1024)
        int c0 = kb + l16, c1 = kb + 16 + l16;
        float p0[4], p1[4], alpha[4];
#pragma unroll
        for (int r = 0; r < 4; r++) {
            int qrow = q0 + quad * 4 + r;
            float v0 = (c0 <= qrow) ? s0[r] * scale : -1.0e10f;
            float v1 = (c1 <= qrow) ? s1[r] * scale : -1.0e10f;
            float mx = fmaxf(v0, v1);
#pragma unroll
            for (int off = 8; off > 0; off >>= 1) mx = fmaxf(mx, __shfl_xor(mx, off, 16));
            float mnew = fmaxf(mI[r], mx);
            float al = __expf(mI[r] - mnew);
            float e0 = __expf(v0 - mnew);
            float e1 = __expf(v1 - mnew);
            float sum = e0 + e1;
#pragma unroll
            for (int off = 8; off > 0; off >>= 1) sum += __shfl_xor(sum, off, 16);
            lI[r] = lI[r] * al + sum;
            mI[r] = mnew;
            p0[r] = e0; p1[r] = e1; alpha[r] = al;
        }
#pragma unroll
        for (int nb = 0; nb < 4; nb++)
#pragma unroll
            for (int r = 0; r < 4; r++) oacc[nb][r] *= alpha[r];

        // P (C-layout) -> LDS -> A-layout fragment (per-wave region, wave-synchronous)
#pragma unroll
        for (int r = 0; r < 4; r++) {
            plds[wv][quad * 4 + r][l16] = f2bf(p0[r]);
            plds[wv][quad * 4 + r][16 + l16] = f2bf(p1[r]);
        }
        bf16x8 pa = *(const bf16x8*)(&plds[wv][l16][quad * 8]);

#pragma unroll
        for (int nb = 0; nb < 4; nb++) {
            bf16x8 vb = *(const bf16x8*)(V + (size_t)(nb * 16 + l16) * SEQ + kb + quad * 8);
            oacc[nb] = mfma16(pa, vb, oacc[nb]);
        }
    }

    // epilogue: write directly in merged layout merged[b][s][i*16+h]
    int b = bh >> 4, h = bh & 15;
#pragma unroll
    for (int nb = 0; nb < 4; nb++) {
#pragma unroll
        for (int r = 0; r < 4; r++) {
            int srow = q0 + quad * 4 + r;
            int ii = nb * 16 + l16;
            float o = oacc[nb][r] / lI[r];
            merged[((size_t)b * SEQ + srow) * DIM + ii * 16 + h] = f2bf(o);
        }
    }
}

// ---------------- output projection GEMM: out[m][n] = sum_k merged[m][k]*owT[n][k] ----------------
__global__ __launch_bounds__(256) void k_out(const ushort_t* __restrict__ a_in,
                                             const ushort_t* __restrict__ wt,
                                             float* __restrict__ out) {
    const int tid = threadIdx.x;
    const int wave = tid >> 6;
    const int lane = tid & 63;
    const int l16 = lane & 15;
    const int quad = lane >> 4;
    const int m0 = blockIdx.x * 128 + (wave & 1) * 64;
    const int n0 = blockIdx.y * 128 + (wave >> 1) * 64;

    const f32x4 zero4 = {0.f, 0.f, 0.f, 0.f};
    f32x4 acc[4][4];
#pragma unroll
    for (int i = 0; i < 4; i++)
#pragma unroll
        for (int j = 0; j < 4; j++) acc[i][j] = zero4;

    const ushort_t* aptr = a_in + (size_t)(m0 + l16) * DIM + quad * 8;
    const ushort_t* bptr = wt   + (size_t)(n0 + l16) * DIM + quad * 8;

    for (int k = 0; k < DIM; k += 32) {
        bf16x8 a[4], b[4];
#pragma unroll
        for (int i = 0; i < 4; i++) {
            a[i] = *(const bf16x8*)(aptr + (size_t)i * 16 * DIM + k);
            b[i] = *(const bf16x8*)(bptr + (size_t)i * 16 * DIM + k);
        }
#pragma unroll
        for (int mi = 0; mi < 4; mi++)
#pragma unroll
            for (int ni = 0; ni < 4; ni++)
                acc[mi][ni] = mfma16(a[mi], b[ni], acc[mi][ni]);
    }

#pragma unroll
    for (int mi = 0; mi < 4; mi++)
#pragma unroll
        for (int ni = 0; ni < 4; ni++) {
            int col = n0 + ni * 16 + l16;
#pragma unroll
            for (int r = 0; r < 4; r++) {
                int row = m0 + mi * 16 + quad * 4 + r;
                out[(size_t)row * DIM + col] = acc[mi][ni][r];
            }
        }
}

extern "C" void kernel_launch(void* const* d_in, const int* in_sizes, int n_in,
                              void* d_out, int out_size, void* d_ws, size_t ws_size,
                              hipStream_t stream) {
    const float* x  = (const float*)d_in[0];
    const float* qw = (const float*)d_in[1];
    const float* kw = (const float*)d_in[2];
    const float* vw = (const float*)d_in[3];
    const float* ow = (const float*)d_in[4];
    float* out = (float*)d_out;

    ushort_t* xb = (ushort_t*)d_ws;                      // 4096*1024
    ushort_t* wt = xb + (size_t)MTOT * DIM;              // 4 * 1024*1024 (q,k,v,o transposed)
    ushort_t* qh = wt + (size_t)4 * DIM * DIM;           // [2][16][2048][64]
    ushort_t* kh = qh + (size_t)BATCH * HEADS * SEQ * HD;
    ushort_t* vt = kh + (size_t)BATCH * HEADS * SEQ * HD; // [2][16][64][2048]
    ushort_t* mg = vt + (size_t)BATCH * HEADS * HD * SEQ; // [4096][1024] merged attn (bf16)

    k_conv_x<<<dim3(MTOT * DIM / 4 / 256), dim3(256), 0, stream>>>(x, xb, MTOT * DIM / 4);
    k_transpose_w<<<dim3(32, 32, 4), dim3(32, 8), 0, stream>>>(qw, kw, vw, ow, wt);
    k_qkv<<<dim3(MTOT / 128, DIM / 128, 3), dim3(256), 0, stream>>>(xb, wt, qh, kh, vt);
    k_attn<<<dim3(SEQ / 64, BATCH * HEADS), dim3(256), 0, stream>>>(qh, kh, vt, mg);
    k_out<<<dim3(MTOT / 128, DIM / 128), dim3(256), 0, stream>>>(mg, wt + (size_t)3 * DIM * DIM, out);
}

// Round 2
// 443.471 us; speedup vs baseline: 1.0959x; 1.0959x over previous
//
#include <hip/hip_runtime.h>
#include <stdint.h>

typedef unsigned short ushort_t;
typedef __bf16 bf16x8 __attribute__((ext_vector_type(8)));
typedef float f32x4 __attribute__((ext_vector_type(4)));

#define DIM 1024
#define HEADS 16
#define HD 64
#define BATCH 2
#define SEQ 2048
#define MTOT (BATCH*SEQ)   // 4096

__device__ __forceinline__ ushort_t f2bf(float f) {
    uint32_t u = __float_as_uint(f);
    uint32_t r = (u + 0x7FFFu + ((u >> 16) & 1u)) >> 16;
    return (ushort_t)r;
}

__device__ __forceinline__ f32x4 mfma16(bf16x8 a, bf16x8 b, f32x4 c) {
    return __builtin_amdgcn_mfma_f32_16x16x32_bf16(a, b, c, 0, 0, 0);
}

// ---------------- convert x: fp32 -> bf16 ----------------
__global__ void k_conv_x(const float* __restrict__ x, ushort_t* __restrict__ xb, int n4) {
    int i = blockIdx.x * blockDim.x + threadIdx.x;
    if (i < n4) {
        const float4 v = ((const float4*)x)[i];
        ushort4 o;
        o.x = f2bf(v.x); o.y = f2bf(v.y); o.z = f2bf(v.z); o.w = f2bf(v.w);
        ((ushort4*)xb)[i] = o;
    }
}

// ---------------- transpose + convert weights, with head-permutation ----------------
// z<3 (q,k,v): wt[n'][k] = bf16(w[k][n]) with n = i*16+h -> n' = h*64+i
//   => GEMM against wt produces output columns already in head-split order.
// z==3 (o):    wt[n][k'] = bf16(w[k][n]) with k = i*16+h -> k' = h*64+i
//   => matches the permuted layout the attention kernel emits.
__global__ void k_transpose_w(const float* __restrict__ w0, const float* __restrict__ w1,
                              const float* __restrict__ w2, const float* __restrict__ w3,
                              ushort_t* __restrict__ wt) {
    __shared__ float t[32][33];
    const int z = blockIdx.z;
    const float* w = (z == 0) ? w0 : (z == 1) ? w1 : (z == 2) ? w2 : w3;
    ushort_t* o = wt + (size_t)z * DIM * DIM;
    int n0 = blockIdx.x * 32;
    int k0 = blockIdx.y * 32;
    int tx = threadIdx.x, ty = threadIdx.y; // (32, 8)
    if (z < 3) {
#pragma unroll
        for (int i = 0; i < 4; i++)
            t[ty + i * 8][tx] = w[(size_t)(k0 + ty + i * 8) * DIM + n0 + tx];
        __syncthreads();
#pragma unroll
        for (int i = 0; i < 4; i++) {
            int n = n0 + ty + i * 8;
            int np = (n & 15) * 64 + (n >> 4);
            o[(size_t)np * DIM + k0 + tx] = f2bf(t[tx][ty + i * 8]);
        }
    } else {
        // here the "k" tile index (k0..k0+31) is k'; fetch source row k = (k'&63)*16 + (k'>>6)
#pragma unroll
        for (int i = 0; i < 4; i++) {
            int kp = k0 + ty + i * 8;
            int k = (kp & 63) * 16 + (kp >> 6);
            t[ty + i * 8][tx] = w[(size_t)k * DIM + n0 + tx];
        }
        __syncthreads();
#pragma unroll
        for (int i = 0; i < 4; i++)
            o[(size_t)(n0 + ty + i * 8) * DIM + k0 + tx] = f2bf(t[tx][ty + i * 8]);
    }
}

// ---------------- fused QKV projection GEMM (coalesced row-major stores) ----------------
// C[m][n'] = sum_k xb[m][k] * wt[z][n'][k];  n' = h*64+i (head-contiguous)
__global__ __launch_bounds__(256) void k_qkv(const ushort_t* __restrict__ xb,
                                             const ushort_t* __restrict__ wt,
                                             ushort_t* __restrict__ qp,
                                             ushort_t* __restrict__ kp,
                                             ushort_t* __restrict__ vp) {
    const int z = blockIdx.z;
    const ushort_t* w = wt + (size_t)z * DIM * DIM;
    ushort_t* dst = (z == 0) ? qp : (z == 1) ? kp : vp;
    const int tid = threadIdx.x;
    const int wave = tid >> 6;
    const int lane = tid & 63;
    const int l16 = lane & 15;
    const int quad = lane >> 4;
    const int m0 = blockIdx.x * 128 + (wave & 1) * 64;
    const int n0 = blockIdx.y * 128 + (wave >> 1) * 64;

    const f32x4 zero4 = {0.f, 0.f, 0.f, 0.f};
    f32x4 acc[4][4];
#pragma unroll
    for (int i = 0; i < 4; i++)
#pragma unroll
        for (int j = 0; j < 4; j++) acc[i][j] = zero4;

    const ushort_t* aptr = xb + (size_t)(m0 + l16) * DIM + quad * 8;
    const ushort_t* bptr = w  + (size_t)(n0 + l16) * DIM + quad * 8;

    for (int k = 0; k < DIM; k += 32) {
        bf16x8 a[4], b[4];
#pragma unroll
        for (int i = 0; i < 4; i++) {
            a[i] = *(const bf16x8*)(aptr + (size_t)i * 16 * DIM + k);
            b[i] = *(const bf16x8*)(bptr + (size_t)i * 16 * DIM + k);
        }
#pragma unroll
        for (int mi = 0; mi < 4; mi++)
#pragma unroll
            for (int ni = 0; ni < 4; ni++)
                acc[mi][ni] = mfma16(a[mi], b[ni], acc[mi][ni]);
    }

#pragma unroll
    for (int mi = 0; mi < 4; mi++)
#pragma unroll
        for (int ni = 0; ni < 4; ni++) {
            int col = n0 + ni * 16 + l16;
#pragma unroll
            for (int r = 0; r < 4; r++) {
                int row = m0 + mi * 16 + quad * 4 + r;
                dst[(size_t)row * DIM + col] = f2bf(acc[mi][ni][r]);
            }
        }
}

// ---------------- V transpose: vt[b][h][i][s] = vp[(b*S+s)*D + h*64+i] ----------------
__global__ void k_vt(const ushort_t* __restrict__ vp, ushort_t* __restrict__ vt) {
    __shared__ ushort_t t[32][34];
    const int bh = blockIdx.z, b = bh >> 4, h = bh & 15;
    const int s0 = blockIdx.x * 32;
    const int i0 = blockIdx.y * 32;
    int tx = threadIdx.x, ty = threadIdx.y; // (32,8)
#pragma unroll
    for (int j = 0; j < 4; j++)
        t[ty + j * 8][tx] = vp[(size_t)(b * SEQ + s0 + ty + j * 8) * DIM + h * HD + i0 + tx];
    __syncthreads();
#pragma unroll
    for (int j = 0; j < 4; j++)
        vt[((size_t)bh * HD + i0 + ty + j * 8) * SEQ + s0 + tx] = t[tx][ty + j * 8];
}

// ---------------- flash attention: 2 waves/block, 16 Q-rows/wave, 64-wide KV tiles ----------------
__global__ __launch_bounds__(128) void k_attn(const ushort_t* __restrict__ qp,
                                              const ushort_t* __restrict__ kp,
                                              const ushort_t* __restrict__ vt,
                                              ushort_t* __restrict__ mg) {
    __shared__ __align__(16) ushort_t plds[2][16][72]; // per-wave P tile (16x64, padded)
    const int tid = threadIdx.x;
    const int wv = tid >> 6;
    const int lane = tid & 63;
    const int l16 = lane & 15;
    const int quad = lane >> 4;
    const int bh = blockIdx.y, b = bh >> 4, h = bh & 15;
    // reversed order: heaviest q-blocks dispatch first (LPT scheduling)
    const int q0 = (gridDim.x - 1 - blockIdx.x) * 32 + wv * 16;

    const ushort_t* Q = qp + (size_t)b * SEQ * DIM + h * HD;
    const ushort_t* K = kp + (size_t)b * SEQ * DIM + h * HD;
    const ushort_t* V = vt + (size_t)bh * HD * SEQ;

    bf16x8 qa0 = *(const bf16x8*)(Q + (size_t)(q0 + l16) * DIM + quad * 8);
    bf16x8 qa1 = *(const bf16x8*)(Q + (size_t)(q0 + l16) * DIM + 32 + quad * 8);

    const f32x4 zero4 = {0.f, 0.f, 0.f, 0.f};
    f32x4 oacc[4];
#pragma unroll
    for (int i = 0; i < 4; i++) oacc[i] = zero4;
    float mI[4], lI[4];
#pragma unroll
    for (int r = 0; r < 4; r++) { mI[r] = -3.0e38f; lI[r] = 0.f; }

    const int nt = (q0 + 79) >> 6; // KV 64-tiles covering [0, q0+16)
    for (int kt = 0; kt < nt; kt++) {
        const int kb = kt * 64;
        // --- S = Q K^T over a 16x64 tile (4 col-subtiles of 16) ---
        f32x4 s[4];
#pragma unroll
        for (int c = 0; c < 4; c++) {
            const ushort_t* kr = K + (size_t)(kb + c * 16 + l16) * DIM;
            bf16x8 k0 = *(const bf16x8*)(kr + quad * 8);
            bf16x8 k1 = *(const bf16x8*)(kr + 32 + quad * 8);
            f32x4 ss = zero4;
            ss = mfma16(qa0, k0, ss);
            ss = mfma16(qa1, k1, ss);
            s[c] = ss;
        }
        // --- V loads issued early (independent of softmax chain) ---
        bf16x8 vb0[4], vb1[4];
#pragma unroll
        for (int nb = 0; nb < 4; nb++) {
            const ushort_t* vr = V + (size_t)(nb * 16 + l16) * SEQ + kb;
            vb0[nb] = *(const bf16x8*)(vr + quad * 8);
            vb1[nb] = *(const bf16x8*)(vr + 32 + quad * 8);
        }
        // --- online softmax over 64 cols ---
        const float scale = 0.03125f; // 1/sqrt(1024)
        const bool need_mask = (kb + 63) > q0; // wave-uniform
        float alpha[4], pE[4][4];
#pragma unroll
        for (int r = 0; r < 4; r++) {
            int qrow = q0 + quad * 4 + r;
            float vv[4];
#pragma unroll
            for (int c = 0; c < 4; c++) {
                float xv = s[c][r] * scale;
                if (need_mask) xv = (kb + c * 16 + l16 <= qrow) ? xv : -1.0e10f;
                vv[c] = xv;
            }
            float mx = fmaxf(fmaxf(vv[0], vv[1]), fmaxf(vv[2], vv[3]));
#pragma unroll
            for (int off = 8; off > 0; off >>= 1) mx = fmaxf(mx, __shfl_xor(mx, off, 16));
            float mnew = fmaxf(mI[r], mx);
            float al = __expf(mI[r] - mnew);
            float sum = 0.f;
#pragma unroll
            for (int c = 0; c < 4; c++) {
                float e = __expf(vv[c] - mnew);
                pE[r][c] = e;
                sum += e;
            }
#pragma unroll
            for (int off = 8; off > 0; off >>= 1) sum += __shfl_xor(sum, off, 16);
            lI[r] = lI[r] * al + sum;
            mI[r] = mnew;
            alpha[r] = al;
        }
#pragma unroll
        for (int nb = 0; nb < 4; nb++)
#pragma unroll
            for (int r = 0; r < 4; r++) oacc[nb][r] *= alpha[r];

        // --- P (C-layout) -> LDS -> A-layout (per-wave, wave-synchronous) ---
#pragma unroll
        for (int r = 0; r < 4; r++)
#pragma unroll
            for (int c = 0; c < 4; c++)
                plds[wv][quad * 4 + r][c * 16 + l16] = f2bf(pE[r][c]);
        bf16x8 pa0 = *(const bf16x8*)(&plds[wv][l16][quad * 8]);
        bf16x8 pa1 = *(const bf16x8*)(&plds[wv][l16][32 + quad * 8]);

#pragma unroll
        for (int nb = 0; nb < 4; nb++) {
            oacc[nb] = mfma16(pa0, vb0[nb], oacc[nb]);
            oacc[nb] = mfma16(pa1, vb1[nb], oacc[nb]);
        }
    }

    // epilogue: coalesced store in permuted merged layout mg[b*S+s][h*64+i]
#pragma unroll
    for (int nb = 0; nb < 4; nb++)
#pragma unroll
        for (int r = 0; r < 4; r++) {
            int srow = q0 + quad * 4 + r;
            mg[((size_t)b * SEQ + srow) * DIM + h * HD + nb * 16 + l16] =
                f2bf(oacc[nb][r] / lI[r]);
        }
}

// ---------------- output projection: out[m][n] = sum_k' mg[m][k'] * owT'[n][k'] ----------------
__global__ __launch_bounds__(256) void k_out(const ushort_t* __restrict__ a_in,
                                             const ushort_t* __restrict__ wt,
                                             float* __restrict__ out) {
    const int tid = threadIdx.x;
    const int wave = tid >> 6;
    const int lane = tid & 63;
    const int l16 = lane & 15;
    const int quad = lane >> 4;
    const int m0 = blockIdx.x * 128 + (wave & 1) * 64;
    const int n0 = blockIdx.y * 128 + (wave >> 1) * 64;

    const f32x4 zero4 = {0.f, 0.f, 0.f, 0.f};
    f32x4 acc[4][4];
#pragma unroll
    for (int i = 0; i < 4; i++)
#pragma unroll
        for (int j = 0; j < 4; j++) acc[i][j] = zero4;

    const ushort_t* aptr = a_in + (size_t)(m0 + l16) * DIM + quad * 8;
    const ushort_t* bptr = wt   + (size_t)(n0 + l16) * DIM + quad * 8;

    for (int k = 0; k < DIM; k += 32) {
        bf16x8 a[4], b[4];
#pragma unroll
        for (int i = 0; i < 4; i++) {
            a[i] = *(const bf16x8*)(aptr + (size_t)i * 16 * DIM + k);
            b[i] = *(const bf16x8*)(bptr + (size_t)i * 16 * DIM + k);
        }
#pragma unroll
        for (int mi = 0; mi < 4; mi++)
#pragma unroll
            for (int ni = 0; ni < 4; ni++)
                acc[mi][ni] = mfma16(a[mi], b[ni], acc[mi][ni]);
    }

#pragma unroll
    for (int mi = 0; mi < 4; mi++)
#pragma unroll
        for (int ni = 0; ni < 4; ni++) {
            int col = n0 + ni * 16 + l16;
#pragma unroll
            for (int r = 0; r < 4; r++) {
                int row = m0 + mi * 16 + quad * 4 + r;
                out[(size_t)row * DIM + col] = acc[mi][ni][r];
            }
        }
}

extern "C" void kernel_launch(void* const* d_in, const int* in_sizes, int n_in,
                              void* d_out, int out_size, void* d_ws, size_t ws_size,
                              hipStream_t stream) {
    const float* x  = (const float*)d_in[0];
    const float* qw = (const float*)d_in[1];
    const float* kw = (const float*)d_in[2];
    const float* vw = (const float*)d_in[3];
    const float* ow = (const float*)d_in[4];
    float* out = (float*)d_out;

    ushort_t* xb = (ushort_t*)d_ws;                      // [4096][1024] bf16 x
    ushort_t* wt = xb + (size_t)MTOT * DIM;              // 4x [1024][1024] permuted weights^T
    ushort_t* qp = wt + (size_t)4 * DIM * DIM;           // [4096][1024] head-permuted Q
    ushort_t* kp = qp + (size_t)MTOT * DIM;              // K
    ushort_t* vp = kp + (size_t)MTOT * DIM;              // V (row-major)
    ushort_t* vt = vp + (size_t)MTOT * DIM;              // [32][64][2048] V^T per head
    ushort_t* mg = xb;                                   // reuse xb: dead after k_qkv

    k_conv_x<<<dim3(MTOT * DIM / 4 / 256), dim3(256), 0, stream>>>(x, xb, MTOT * DIM / 4);
    k_transpose_w<<<dim3(32, 32, 4), dim3(32, 8), 0, stream>>>(qw, kw, vw, ow, wt);
    k_qkv<<<dim3(MTOT / 128, DIM / 128, 3), dim3(256), 0, stream>>>(xb, wt, qp, kp, vp);
    k_vt<<<dim3(SEQ / 32, HD / 32, BATCH * HEADS), dim3(32, 8), 0, stream>>>(vp, vt);
    k_attn<<<dim3(SEQ / 32, BATCH * HEADS), dim3(128), 0, stream>>>(qp, kp, vt, mg);
    k_out<<<dim3(MTOT / 128, DIM / 128), dim3(256), 0, stream>>>(mg, wt + (size_t)3 * DIM * DIM, out);
}

// Round 3
// 256.858 us; speedup vs baseline: 1.8921x; 1.7265x over previous
//
#include <hip/hip_runtime.h>
#include <stdint.h>

typedef unsigned short ushort_t;
typedef __bf16 bf16x8 __attribute__((ext_vector_type(8)));
typedef float f32x4 __attribute__((ext_vector_type(4)));

#define DIM 1024
#define HEADS 16
#define HD 64
#define BATCH 2
#define SEQ 2048
#define MTOT (BATCH*SEQ)   // 4096

__device__ __forceinline__ ushort_t f2bf(float f) {
    uint32_t u = __float_as_uint(f);
    uint32_t r = (u + 0x7FFFu + ((u >> 16) & 1u)) >> 16;
    return (ushort_t)r;
}

__device__ __forceinline__ uint32_t pack2bf(float a, float b) {
    return ((uint32_t)f2bf(b) << 16) | (uint32_t)f2bf(a);
}

__device__ __forceinline__ f32x4 mfma16(bf16x8 a, bf16x8 b, f32x4 c) {
    return __builtin_amdgcn_mfma_f32_16x16x32_bf16(a, b, c, 0, 0, 0);
}

// async global->LDS, 16B per lane; LDS dest = wave-uniform base + lane*16
__device__ __forceinline__ void glds16(const ushort_t* g, ushort_t* l) {
    __builtin_amdgcn_global_load_lds(
        (const __attribute__((address_space(1))) unsigned int*)g,
        (__attribute__((address_space(3))) unsigned int*)l, 16, 0, 0);
}

// ---------------- convert x: fp32 -> bf16 ----------------
__global__ void k_conv_x(const float* __restrict__ x, ushort_t* __restrict__ xb, int n4) {
    int i = blockIdx.x * blockDim.x + threadIdx.x;
    if (i < n4) {
        const float4 v = ((const float4*)x)[i];
        ushort4 o;
        o.x = f2bf(v.x); o.y = f2bf(v.y); o.z = f2bf(v.z); o.w = f2bf(v.w);
        ((ushort4*)xb)[i] = o;
    }
}

// ---------------- transpose + convert weights, with head-permutation ----------------
// z<3 (q,k,v): wt[n'][k] = bf16(w[k][n]), n=i*16+h -> n'=h*64+i
// z==3 (o):    wt[n][k'] = bf16(w[k][n]), k=i*16+h -> k'=h*64+i
__global__ void k_transpose_w(const float* __restrict__ w0, const float* __restrict__ w1,
                              const float* __restrict__ w2, const float* __restrict__ w3,
                              ushort_t* __restrict__ wt) {
    __shared__ float t[32][33];
    const int z = blockIdx.z;
    const float* w = (z == 0) ? w0 : (z == 1) ? w1 : (z == 2) ? w2 : w3;
    ushort_t* o = wt + (size_t)z * DIM * DIM;
    int n0 = blockIdx.x * 32;
    int k0 = blockIdx.y * 32;
    int tx = threadIdx.x, ty = threadIdx.y; // (32, 8)
    if (z < 3) {
#pragma unroll
        for (int i = 0; i < 4; i++)
            t[ty + i * 8][tx] = w[(size_t)(k0 + ty + i * 8) * DIM + n0 + tx];
        __syncthreads();
#pragma unroll
        for (int i = 0; i < 4; i++) {
            int n = n0 + ty + i * 8;
            int np = (n & 15) * 64 + (n >> 4);
            o[(size_t)np * DIM + k0 + tx] = f2bf(t[tx][ty + i * 8]);
        }
    } else {
#pragma unroll
        for (int i = 0; i < 4; i++) {
            int kp = k0 + ty + i * 8;
            int k = (kp & 63) * 16 + (kp >> 6);
            t[ty + i * 8][tx] = w[(size_t)k * DIM + n0 + tx];
        }
        __syncthreads();
#pragma unroll
        for (int i = 0; i < 4; i++)
            o[(size_t)(n0 + ty + i * 8) * DIM + k0 + tx] = f2bf(t[tx][ty + i * 8]);
    }
}

// ---------------- m97-style GEMM core: C[m][n] = sum_k A[m][k]*B[n][k] ----------------
// 128x128 tile, BK=32, global_load_lds w16, XOR-swizzled LDS chunks.
// LDS tile: 128 rows x 32 shorts; chunk L = row*4+cd holds global chunk cd^((row>>1)&3).
__device__ __forceinline__ void gemm_tile_nt(const ushort_t* __restrict__ A,
                                             const ushort_t* __restrict__ B,
                                             ushort_t* lA, ushort_t* lB,
                                             int m0, int n0, f32x4 acc[4][4]) {
    const int tid = threadIdx.x;
    const int w = tid >> 6;
    const int lane = tid & 63;
    const int l16 = lane & 15;
    const int quad = lane >> 4;
    const int swz = (l16 >> 1) & 3;

    for (int k0 = 0; k0 < DIM; k0 += 32) {
        __syncthreads();
#pragma unroll
        for (int j = 0; j < 2; j++) {
            int base = w * 128 + j * 64;
            int L = base + lane;
            int row = L >> 2, cd = L & 3;
            int cs = cd ^ ((row >> 1) & 3);
            glds16(A + (size_t)(m0 + row) * DIM + k0 + cs * 8, lA + base * 8);
            glds16(B + (size_t)(n0 + row) * DIM + k0 + cs * 8, lB + base * 8);
        }
        __syncthreads();
        bf16x8 a[4], b[4];
#pragma unroll
        for (int i = 0; i < 4; i++) {
            int row = i * 16 + l16;
            int ch = quad ^ swz;
            a[i] = *(const bf16x8*)(lA + row * 32 + ch * 8);
            b[i] = *(const bf16x8*)(lB + row * 32 + ch * 8);
        }
#pragma unroll
        for (int mi = 0; mi < 4; mi++)
#pragma unroll
            for (int ni = 0; ni < 4; ni++)
                acc[mi][ni] = mfma16(a[mi], b[ni], acc[mi][ni]);
    }
}

// ---------------- fused QKV projection GEMM ----------------
__global__ __launch_bounds__(256) void k_qkv(const ushort_t* __restrict__ xb,
                                             const ushort_t* __restrict__ wt,
                                             ushort_t* __restrict__ qp,
                                             ushort_t* __restrict__ kp,
                                             ushort_t* __restrict__ vp) {
    __shared__ __align__(16) ushort_t lA[128 * 32];
    __shared__ __align__(16) ushort_t lB[128 * 32];
    const int z = blockIdx.z;
    const ushort_t* w = wt + (size_t)z * DIM * DIM;
    ushort_t* dst = (z == 0) ? qp : (z == 1) ? kp : vp;
    const int tid = threadIdx.x;
    const int wave = tid >> 6;
    const int lane = tid & 63;
    const int l16 = lane & 15;
    const int quad = lane >> 4;
    const int m0 = blockIdx.x * 128;
    const int n0 = blockIdx.y * 128;
    const int mw = (wave & 1) * 64, nw = (wave >> 1) * 64;

    const f32x4 zero4 = {0.f, 0.f, 0.f, 0.f};
    f32x4 acc[4][4];
#pragma unroll
    for (int i = 0; i < 4; i++)
#pragma unroll
        for (int j = 0; j < 4; j++) acc[i][j] = zero4;

    // per-wave subtile offsets are folded into the fragment row: wave (mw,nw)
    // reads rows mw+mi*16+l16 of lA / nw+ni*16+l16 of lB.
    {
        const int swz = (l16 >> 1) & 3;
        for (int k0 = 0; k0 < DIM; k0 += 32) {
            __syncthreads();
#pragma unroll
            for (int j = 0; j < 2; j++) {
                int base = wave * 128 + j * 64;
                int L = base + lane;
                int row = L >> 2, cd = L & 3;
                int cs = cd ^ ((row >> 1) & 3);
                glds16(xb + (size_t)(m0 + row) * DIM + k0 + cs * 8, lA + base * 8);
                glds16(w + (size_t)(n0 + row) * DIM + k0 + cs * 8, lB + base * 8);
            }
            __syncthreads();
            bf16x8 a[4], b[4];
#pragma unroll
            for (int i = 0; i < 4; i++) {
                int rowa = mw + i * 16 + l16;
                int rowb = nw + i * 16 + l16;
                int ch = quad ^ swz;
                a[i] = *(const bf16x8*)(lA + rowa * 32 + ch * 8);
                b[i] = *(const bf16x8*)(lB + rowb * 32 + ch * 8);
            }
#pragma unroll
            for (int mi = 0; mi < 4; mi++)
#pragma unroll
                for (int ni = 0; ni < 4; ni++)
                    acc[mi][ni] = mfma16(a[mi], b[ni], acc[mi][ni]);
        }
    }

#pragma unroll
    for (int mi = 0; mi < 4; mi++)
#pragma unroll
        for (int ni = 0; ni < 4; ni++) {
            int col = n0 + nw + ni * 16 + l16;
#pragma unroll
            for (int r = 0; r < 4; r++) {
                int row = m0 + mw + mi * 16 + quad * 4 + r;
                dst[(size_t)row * DIM + col] = f2bf(acc[mi][ni][r]);
            }
        }
}

// ---------------- V transpose: vt[bh][i][s] = vp[(b*S+s)*D + h*64+i] ----------------
__global__ void k_vt(const ushort_t* __restrict__ vp, ushort_t* __restrict__ vt) {
    __shared__ ushort_t t[32][34];
    const int bh = blockIdx.z, b = bh >> 4, h = bh & 15;
    const int s0 = blockIdx.x * 32;
    const int i0 = blockIdx.y * 32;
    int tx = threadIdx.x, ty = threadIdx.y; // (32,8)
#pragma unroll
    for (int j = 0; j < 4; j++)
        t[ty + j * 8][tx] = vp[(size_t)(b * SEQ + s0 + ty + j * 8) * DIM + h * HD + i0 + tx];
    __syncthreads();
#pragma unroll
    for (int j = 0; j < 4; j++)
        vt[((size_t)bh * HD + i0 + ty + j * 8) * SEQ + s0 + tx] = t[tx][ty + j * 8];
}

// ---------------- flash attention, transposed-score formulation ----------------
// Block: 256 thr / 4 waves; 128 Q-rows per block (32 per wave, 2 m-subtiles).
// K/V tiles (64 wide) staged to LDS via global_load_lds with XOR swizzle.
// S^T = K Q^T  (softmax reduce = per-lane over 16 regs + 2 quad shuffles)
// O^T = V^T P^T (P^T B-frags built by 8 shuffles + selects per m/pair)
__global__ __launch_bounds__(256) void k_attn(const ushort_t* __restrict__ qp,
                                              const ushort_t* __restrict__ kp,
                                              const ushort_t* __restrict__ vt,
                                              ushort_t* __restrict__ mg) {
    __shared__ __align__(16) ushort_t lK[64 * 64]; // 64 rows x 128B
    __shared__ __align__(16) ushort_t lV[64 * 64];
    const int tid = threadIdx.x;
    const int w = tid >> 6;
    const int lane = tid & 63;
    const int l16 = lane & 15;
    const int quad = lane >> 4;
    const int bh = blockIdx.y, b = bh >> 4, h = bh & 15;
    const int qb = (gridDim.x - 1 - blockIdx.x) * 128; // LPT: heaviest first

    const ushort_t* Q = qp + (size_t)b * SEQ * DIM + h * HD;
    const ushort_t* K = kp + (size_t)b * SEQ * DIM + h * HD;
    const ushort_t* V = vt + (size_t)bh * HD * SEQ;

    const int mb0 = qb + w * 32;

    // Q fragments (B-operand: lane l16 -> q-row, quad*8+j -> hd)
    bf16x8 qf[2][2];
#pragma unroll
    for (int m = 0; m < 2; m++)
#pragma unroll
        for (int hf = 0; hf < 2; hf++)
            qf[m][hf] = *(const bf16x8*)(Q + (size_t)(mb0 + m * 16 + l16) * DIM + hf * 32 + quad * 8);

    const f32x4 zero4 = {0.f, 0.f, 0.f, 0.f};
    f32x4 oT[2][4];
#pragma unroll
    for (int m = 0; m < 2; m++)
#pragma unroll
        for (int nb = 0; nb < 4; nb++) oT[m][nb] = zero4;
    float mI[2] = {-1.0e30f, -1.0e30f}, lI[2] = {0.f, 0.f};

    const int swz = l16 & 7;
    const int nt = (qb >> 6) + 2;
    for (int kt = 0; kt < nt; kt++) {
        const int kb = kt * 64;
        __syncthreads();
        // stage K,V tiles (8KB each): chunk L=row*8+cd holds global chunk cd^(row&7)
#pragma unroll
        for (int j = 0; j < 2; j++) {
            int base = w * 128 + j * 64;
            int L = base + lane;
            int row = L >> 3, cd = L & 7;
            int cs = cd ^ (row & 7);
            glds16(K + (size_t)(kb + row) * DIM + cs * 8, lK + base * 8);
            glds16(V + (size_t)row * SEQ + kb + cs * 8, lV + base * 8);
        }
        __syncthreads();
        if (kb <= mb0 + 31) {
            // K frags (A-operand: l16 -> k-seq row, quad*8+j -> hd)
            bf16x8 kf[4][2], vf[4][2];
#pragma unroll
            for (int c = 0; c < 4; c++)
#pragma unroll
                for (int hf = 0; hf < 2; hf++) {
                    int row = c * 16 + l16;
                    int ch = (hf * 4 + quad) ^ swz;
                    kf[c][hf] = *(const bf16x8*)(lK + row * 64 + ch * 8);
                }
            // V^T frags (A-operand: l16 -> v-dim row, quad*8+j -> seq)
#pragma unroll
            for (int nb = 0; nb < 4; nb++)
#pragma unroll
                for (int pr = 0; pr < 2; pr++) {
                    int row = nb * 16 + l16;
                    int ch = (pr * 4 + quad) ^ swz;
                    vf[nb][pr] = *(const bf16x8*)(lV + row * 64 + ch * 8);
                }
#pragma unroll
            for (int m = 0; m < 2; m++) {
                const int mb = mb0 + m * 16;
                if (kb > mb + 15) continue; // wave-uniform
                // S^T tiles: C row = quad*4+r (k-seq), col = l16 (q-row)
                f32x4 s4[4];
#pragma unroll
                for (int c = 0; c < 4; c++) {
                    f32x4 t = zero4;
                    t = mfma16(kf[c][0], qf[m][0], t);
                    t = mfma16(kf[c][1], qf[m][1], t);
                    s4[c] = t;
                }
                const float C2 = 0.04508453421137f; // log2(e)/32
                const int qrow = mb + l16;
                const bool needmask = (kb + 63 > mb);
                float p[4][4];
                float vmax = -1.0e30f;
#pragma unroll
                for (int c = 0; c < 4; c++)
#pragma unroll
                    for (int r = 0; r < 4; r++) {
                        int k = kb + c * 16 + quad * 4 + r;
                        float v = s4[c][r] * C2;
                        if (needmask && k > qrow) v = -1.0e30f;
                        p[c][r] = v;
                        vmax = fmaxf(vmax, v);
                    }
                vmax = fmaxf(vmax, __shfl_xor(vmax, 16));
                vmax = fmaxf(vmax, __shfl_xor(vmax, 32));
                float mnew = fmaxf(mI[m], vmax);
                float al = exp2f(mI[m] - mnew);
                mI[m] = mnew;
                float sum = 0.f;
#pragma unroll
                for (int c = 0; c < 4; c++)
#pragma unroll
                    for (int r = 0; r < 4; r++) {
                        float e = exp2f(p[c][r] - mnew);
                        p[c][r] = e;
                        sum += e;
                    }
                sum += __shfl_xor(sum, 16);
                sum += __shfl_xor(sum, 32);
                lI[m] = lI[m] * al + sum;
#pragma unroll
                for (int nb = 0; nb < 4; nb++) oT[m][nb] *= al;
                // pack P to bf16 pairs: pk[c][0]=r0,r1  pk[c][1]=r2,r3
                uint32_t pk[4][2];
#pragma unroll
                for (int c = 0; c < 4; c++) {
                    pk[c][0] = pack2bf(p[c][0], p[c][1]);
                    pk[c][1] = pack2bf(p[c][2], p[c][3]);
                }
                // build P^T B-frags and accumulate O^T
                const int sA = ((quad & 1) * 2) * 16 + l16;
                const int sB = sA + 16;
                const bool hi = (quad >> 1) != 0;
#pragma unroll
                for (int pr = 0; pr < 2; pr++) {
                    int c0 = pr * 2, c1 = pr * 2 + 1;
                    uint32_t x00 = (uint32_t)__shfl((int)pk[c0][0], sA);
                    uint32_t x01 = (uint32_t)__shfl((int)pk[c1][0], sA);
                    uint32_t x10 = (uint32_t)__shfl((int)pk[c0][1], sA);
                    uint32_t x11 = (uint32_t)__shfl((int)pk[c1][1], sA);
                    uint32_t x20 = (uint32_t)__shfl((int)pk[c0][0], sB);
                    uint32_t x21 = (uint32_t)__shfl((int)pk[c1][0], sB);
                    uint32_t x30 = (uint32_t)__shfl((int)pk[c0][1], sB);
                    uint32_t x31 = (uint32_t)__shfl((int)pk[c1][1], sB);
                    union { uint32_t u[4]; bf16x8 v; } pu;
                    pu.u[0] = hi ? x01 : x00;
                    pu.u[1] = hi ? x11 : x10;
                    pu.u[2] = hi ? x21 : x20;
                    pu.u[3] = hi ? x31 : x30;
#pragma unroll
                    for (int nb = 0; nb < 4; nb++)
                        oT[m][nb] = mfma16(vf[nb][pr], pu.v, oT[m][nb]);
                }
            }
        }
    }

    // epilogue: O^T row = v-dim (quad*4+r), col = q (l16); 4 bf16 per 8B store
#pragma unroll
    for (int m = 0; m < 2; m++) {
        float inv = 1.0f / lI[m];
        int srow = mb0 + m * 16 + l16;
#pragma unroll
        for (int nb = 0; nb < 4; nb++) {
            ushort4 o;
            o.x = f2bf(oT[m][nb][0] * inv);
            o.y = f2bf(oT[m][nb][1] * inv);
            o.z = f2bf(oT[m][nb][2] * inv);
            o.w = f2bf(oT[m][nb][3] * inv);
            *(ushort4*)(mg + ((size_t)b * SEQ + srow) * DIM + h * HD + nb * 16 + quad * 4) = o;
        }
    }
}

// ---------------- output projection (m97 structure, fp32 out) ----------------
__global__ __launch_bounds__(256) void k_out(const ushort_t* __restrict__ a_in,
                                             const ushort_t* __restrict__ wt,
                                             float* __restrict__ out) {
    __shared__ __align__(16) ushort_t lA[128 * 32];
    __shared__ __align__(16) ushort_t lB[128 * 32];
    const int tid = threadIdx.x;
    const int wave = tid >> 6;
    const int lane = tid & 63;
    const int l16 = lane & 15;
    const int quad = lane >> 4;
    const int m0 = blockIdx.x * 128;
    const int n0 = blockIdx.y * 128;
    const int mw = (wave & 1) * 64, nw = (wave >> 1) * 64;

    const f32x4 zero4 = {0.f, 0.f, 0.f, 0.f};
    f32x4 acc[4][4];
#pragma unroll
    for (int i = 0; i < 4; i++)
#pragma unroll
        for (int j = 0; j < 4; j++) acc[i][j] = zero4;

    const int swz = (l16 >> 1) & 3;
    for (int k0 = 0; k0 < DIM; k0 += 32) {
        __syncthreads();
#pragma unroll
        for (int j = 0; j < 2; j++) {
            int base = wave * 128 + j * 64;
            int L = base + lane;
            int row = L >> 2, cd = L & 3;
            int cs = cd ^ ((row >> 1) & 3);
            glds16(a_in + (size_t)(m0 + row) * DIM + k0 + cs * 8, lA + base * 8);
            glds16(wt + (size_t)(n0 + row) * DIM + k0 + cs * 8, lB + base * 8);
        }
        __syncthreads();
        bf16x8 a[4], b[4];
#pragma unroll
        for (int i = 0; i < 4; i++) {
            int rowa = mw + i * 16 + l16;
            int rowb = nw + i * 16 + l16;
            int ch = quad ^ swz;
            a[i] = *(const bf16x8*)(lA + rowa * 32 + ch * 8);
            b[i] = *(const bf16x8*)(lB + rowb * 32 + ch * 8);
        }
#pragma unroll
        for (int mi = 0; mi < 4; mi++)
#pragma unroll
            for (int ni = 0; ni < 4; ni++)
                acc[mi][ni] = mfma16(a[mi], b[ni], acc[mi][ni]);
    }

#pragma unroll
    for (int mi = 0; mi < 4; mi++)
#pragma unroll
        for (int ni = 0; ni < 4; ni++) {
            int col = n0 + nw + ni * 16 + l16;
#pragma unroll
            for (int r = 0; r < 4; r++) {
                int row = m0 + mw + mi * 16 + quad * 4 + r;
                out[(size_t)row * DIM + col] = acc[mi][ni][r];
            }
        }
}

extern "C" void kernel_launch(void* const* d_in, const int* in_sizes, int n_in,
                              void* d_out, int out_size, void* d_ws, size_t ws_size,
                              hipStream_t stream) {
    const float* x  = (const float*)d_in[0];
    const float* qw = (const float*)d_in[1];
    const float* kw = (const float*)d_in[2];
    const float* vw = (const float*)d_in[3];
    const float* ow = (const float*)d_in[4];
    float* out = (float*)d_out;

    ushort_t* xb = (ushort_t*)d_ws;                      // [4096][1024] bf16 x
    ushort_t* wt = xb + (size_t)MTOT * DIM;              // 4x [1024][1024] permuted weights^T
    ushort_t* qp = wt + (size_t)4 * DIM * DIM;           // [4096][1024] head-permuted Q
    ushort_t* kp = qp + (size_t)MTOT * DIM;              // K
    ushort_t* vp = kp + (size_t)MTOT * DIM;              // V (row-major)
    ushort_t* vt = vp + (size_t)MTOT * DIM;              // [32][64][2048] V^T per head
    ushort_t* mg = xb;                                   // reuse xb: dead after k_qkv

    k_conv_x<<<dim3(MTOT * DIM / 4 / 256), dim3(256), 0, stream>>>(x, xb, MTOT * DIM / 4);
    k_transpose_w<<<dim3(32, 32, 4), dim3(32, 8), 0, stream>>>(qw, kw, vw, ow, wt);
    k_qkv<<<dim3(MTOT / 128, DIM / 128, 3), dim3(256), 0, stream>>>(xb, wt, qp, kp, vp);
    k_vt<<<dim3(SEQ / 32, HD / 32, BATCH * HEADS), dim3(32, 8), 0, stream>>>(vp, vt);
    k_attn<<<dim3(SEQ / 128, BATCH * HEADS), dim3(256), 0, stream>>>(qp, kp, vt, mg);
    k_out<<<dim3(MTOT / 128, DIM / 128), dim3(256), 0, stream>>>(mg, wt + (size_t)3 * DIM * DIM, out);
}